// Round 3
// baseline (267.188 us; speedup 1.0000x reference)
//
#include <hip/hip_runtime.h>

// Forward kinematics, H36M 17-joint skeleton.
// One thread = one sample.
// R6 change: delete LDS staging entirely; store results directly to global as
// 51 fire-and-forget dword stores per thread.
// R5 post-mortem: two-phase LDS split raised occupancy (25->46%) but the
// compiler spilled the ~76 floats carried across the phase barrier
// (VGPR 68->40, FETCH +21MB, WRITE +34MB of scratch traffic) -> 100us.
// Root cause of the 12-wave/CU cap was the staging buffer itself:
// 204 B/thread -> 160KB/(204*64) = 12 waves/CU regardless of block size.
// LDS staging existed only for store coalescing; a wave's 51 store instrs
// densely cover one contiguous 13KB region, so L2 lines become fully dirty
// within the burst -- TCC byte-enable write-miss handling should keep
// WRITE_SIZE exact (this round is the direct test of that).
// With LDS=0, VGPR=68: 7 waves/SIMD = 28 waves/CU (87.5% occupancy), no
// barriers, no LDS round-trip, single-phase register schedule (no spills).

#define NB 128

__device__ __forceinline__ void mm3(const float A[9], const float B[9], float C[9]) {
#pragma unroll
    for (int r = 0; r < 3; ++r) {
        C[3*r+0] = A[3*r+0]*B[0] + A[3*r+1]*B[3] + A[3*r+2]*B[6];
        C[3*r+1] = A[3*r+0]*B[1] + A[3*r+1]*B[4] + A[3*r+2]*B[7];
        C[3*r+2] = A[3*r+0]*B[2] + A[3*r+1]*B[5] + A[3*r+2]*B[8];
    }
}

// R = Rx(a) @ Ry(b) @ Rz(c)  (pytorch3d euler_angles_to_matrix 'XYZ'), row-major
__device__ __forceinline__ void euler_rot(const float* __restrict__ ev, int i, float R[9]) {
    float a = ev[3*i+0], b = ev[3*i+1], c = ev[3*i+2];
    float sx, cx, sy, cy, sz, cz;
    __sincosf(a, &sx, &cx);
    __sincosf(b, &sy, &cy);
    __sincosf(c, &sz, &cz);
    R[0] = cy*cz;             R[1] = -cy*sz;            R[2] = sy;
    R[3] = sx*sy*cz + cx*sz;  R[4] = -sx*sy*sz + cx*cz; R[5] = -sx*cy;
    R[6] = -cx*sy*cz + sx*sz; R[7] = cx*sy*sz + sx*cz;  R[8] = cx*cy;
}

__global__ void __launch_bounds__(NB)
fk17_kernel(const float* __restrict__ euler, const float* __restrict__ blen,
            float* __restrict__ out, int n)
{
    const int tid    = threadIdx.x;
    const int block0 = blockIdx.x * NB;
    const int t      = block0 + tid;

    if (t >= n) return;

    // ---- batched input loads: 12 + 4 independent float4s ----
    float ev[48];
    const float4* ge4 = (const float4*)(euler + (size_t)t * 48);
#pragma unroll
    for (int q = 0; q < 12; ++q) {
        float4 v = ge4[q];
        ev[4*q+0] = v.x; ev[4*q+1] = v.y; ev[4*q+2] = v.z; ev[4*q+3] = v.w;
    }
    float L[16];
    const float4* gb4 = (const float4*)(blen + (size_t)t * 16);
#pragma unroll
    for (int q = 0; q < 4; ++q) {
        float4 v = gb4[q];
        L[4*q+0] = v.x; L[4*q+1] = v.y; L[4*q+2] = v.z; L[4*q+3] = v.w;
    }

    // ---- direct global stores, fire-and-forget ----
    float* o = out + (size_t)t * 51;
    float Ma[9], Mb[9], M8[9], R[9];
    float px, py, pz, p8x, p8y, p8z;

    // root (joint 0)
    o[0] = 0.f; o[1] = 0.f; o[2] = 0.f;

    // --- chain: 0 -> 1 -> 2 -> 3 (bones 0,1,2) ---
    euler_rot(ev, 0, Ma);                        // M1 = I @ R0
    px = L[0]*Ma[6]; py = L[0]*Ma[7]; pz = L[0]*Ma[8];
    o[3] = px; o[4] = py; o[5] = pz;
    euler_rot(ev, 1, R); mm3(Ma, R, Mb);
    px += L[1]*Mb[6]; py += L[1]*Mb[7]; pz += L[1]*Mb[8];
    o[6] = px; o[7] = py; o[8] = pz;
    euler_rot(ev, 2, R); mm3(Mb, R, Ma);
    px += L[2]*Ma[6]; py += L[2]*Ma[7]; pz += L[2]*Ma[8];
    o[9] = px; o[10] = py; o[11] = pz;

    // --- chain: 0 -> 4 -> 5 -> 6 (bones 3,4,5) ---
    euler_rot(ev, 3, Ma);
    px = L[3]*Ma[6]; py = L[3]*Ma[7]; pz = L[3]*Ma[8];
    o[12] = px; o[13] = py; o[14] = pz;
    euler_rot(ev, 4, R); mm3(Ma, R, Mb);
    px += L[4]*Mb[6]; py += L[4]*Mb[7]; pz += L[4]*Mb[8];
    o[15] = px; o[16] = py; o[17] = pz;
    euler_rot(ev, 5, R); mm3(Mb, R, Ma);
    px += L[5]*Ma[6]; py += L[5]*Ma[7]; pz += L[5]*Ma[8];
    o[18] = px; o[19] = py; o[20] = pz;

    // --- spine: 0 -> 7 -> 8 (bones 6,7) ---
    euler_rot(ev, 6, Ma);
    px = L[6]*Ma[6]; py = L[6]*Ma[7]; pz = L[6]*Ma[8];
    o[21] = px; o[22] = py; o[23] = pz;
    euler_rot(ev, 7, R); mm3(Ma, R, M8);         // M8 = accum at joint 8
    px += L[7]*M8[6]; py += L[7]*M8[7]; pz += L[7]*M8[8];
    o[24] = px; o[25] = py; o[26] = pz;
    p8x = px; p8y = py; p8z = pz;

    // --- branch: 8 -> 9 -> 10 (bones 8,9) ---
    euler_rot(ev, 8, R); mm3(M8, R, Ma);
    px = p8x + L[8]*Ma[6]; py = p8y + L[8]*Ma[7]; pz = p8z + L[8]*Ma[8];
    o[27] = px; o[28] = py; o[29] = pz;
    euler_rot(ev, 9, R); mm3(Ma, R, Mb);
    px += L[9]*Mb[6]; py += L[9]*Mb[7]; pz += L[9]*Mb[8];
    o[30] = px; o[31] = py; o[32] = pz;

    // --- branch: 8 -> 11 -> 12 -> 13 (bones 10,11,12) ---
    euler_rot(ev, 10, R); mm3(M8, R, Ma);
    px = p8x + L[10]*Ma[6]; py = p8y + L[10]*Ma[7]; pz = p8z + L[10]*Ma[8];
    o[33] = px; o[34] = py; o[35] = pz;
    euler_rot(ev, 11, R); mm3(Ma, R, Mb);
    px += L[11]*Mb[6]; py += L[11]*Mb[7]; pz += L[11]*Mb[8];
    o[36] = px; o[37] = py; o[38] = pz;
    euler_rot(ev, 12, R); mm3(Mb, R, Ma);
    px += L[12]*Ma[6]; py += L[12]*Ma[7]; pz += L[12]*Ma[8];
    o[39] = px; o[40] = py; o[41] = pz;

    // --- branch: 8 -> 14 -> 15 -> 16 (bones 13,14,15) ---
    euler_rot(ev, 13, R); mm3(M8, R, Ma);
    px = p8x + L[13]*Ma[6]; py = p8y + L[13]*Ma[7]; pz = p8z + L[13]*Ma[8];
    o[42] = px; o[43] = py; o[44] = pz;
    euler_rot(ev, 14, R); mm3(Ma, R, Mb);
    px += L[14]*Mb[6]; py += L[14]*Mb[7]; pz += L[14]*Mb[8];
    o[45] = px; o[46] = py; o[47] = pz;
    euler_rot(ev, 15, R); mm3(Mb, R, Ma);
    px += L[15]*Ma[6]; py += L[15]*Ma[7]; pz += L[15]*Ma[8];
    o[48] = px; o[49] = py; o[50] = pz;
}

extern "C" void kernel_launch(void* const* d_in, const int* in_sizes, int n_in,
                              void* d_out, int out_size, void* d_ws, size_t ws_size,
                              hipStream_t stream) {
    const float* euler = (const float*)d_in[0];   // (N,16,3) fp32
    const float* blen  = (const float*)d_in[1];   // (N,16,1) fp32
    float* out = (float*)d_out;                   // (N,17,3) fp32

    const int n    = in_sizes[0] / 48;
    const int grid = (n + NB - 1) / NB;
    fk17_kernel<<<grid, NB, 0, stream>>>(euler, blen, out, n);
}

// Round 4
// 254.139 us; speedup vs baseline: 1.0513x; 1.0513x over previous
//
#include <hip/hip_runtime.h>

// Forward kinematics, H36M 17-joint skeleton. One thread = one sample.
// R7: two-phase LDS-staged output (joints 0..8 then 9..16) reusing ONE
// 128x27 buffer -> LDS 13824 B -> 11 blocks/CU = 22 waves/CU (vs 12 for the
// single-phase 51-float stage).
// R5 post-mortem: the split itself was right; the 100us came entirely from
// the compiler spilling cross-barrier state (VGPR 40 + ~55MB scratch traffic,
// which at 2.3TB/s predicts the regression exactly). R6 proved direct global
// stores read-allocate (WRITE 202MB, FETCH +67MB) -> staging is mandatory.
// R7 makes spill structurally impossible: ZERO floats live across barriers.
// Phase B reloads its inputs (L2-hit, just-touched lines) and RECOMPUTES
// M8/p8 from bones 6,7 (~100 VALU ops, free at 12% VALUBusy). Every phase is
// a self-contained if-block; only SGPRs (tid/block0/nvalid) cross barriers.
// Drains: scalar dword, lane-consecutive -> coalesced global, conflict-free
// LDS. Stride 27 (odd) for compute-phase writes -> 2-way max = free.

#define NB 128
#define CA 27  // joints 0..8  floats/sample; also LDS stride
#define CB 24  // joints 9..16 floats/sample

__device__ __forceinline__ void mm3(const float A[9], const float B[9], float C[9]) {
#pragma unroll
    for (int r = 0; r < 3; ++r) {
        C[3*r+0] = A[3*r+0]*B[0] + A[3*r+1]*B[3] + A[3*r+2]*B[6];
        C[3*r+1] = A[3*r+0]*B[1] + A[3*r+1]*B[4] + A[3*r+2]*B[7];
        C[3*r+2] = A[3*r+0]*B[2] + A[3*r+1]*B[5] + A[3*r+2]*B[8];
    }
}

// R = Rx(a) @ Ry(b) @ Rz(c)  (pytorch3d euler_angles_to_matrix 'XYZ'), row-major
__device__ __forceinline__ void euler_rot3(const float* __restrict__ e, float R[9]) {
    float a = e[0], b = e[1], c = e[2];
    float sx, cx, sy, cy, sz, cz;
    __sincosf(a, &sx, &cx);
    __sincosf(b, &sy, &cy);
    __sincosf(c, &sz, &cz);
    R[0] = cy*cz;             R[1] = -cy*sz;            R[2] = sy;
    R[3] = sx*sy*cz + cx*sz;  R[4] = -sx*sy*sz + cx*cz; R[5] = -sx*cy;
    R[6] = -cx*sy*cz + sx*sz; R[7] = cx*sy*sz + sx*cz;  R[8] = cx*cy;
}

__global__ void __launch_bounds__(NB, 5)
fk17_kernel(const float* __restrict__ euler, const float* __restrict__ blen,
            float* __restrict__ out, int n)
{
    __shared__ float s_o[NB * CA];  // 13824 B

    const int tid    = threadIdx.x;
    const int block0 = blockIdx.x * NB;
    const int nvalid = min(NB, n - block0);
    const int t      = block0 + tid;

    // ================= phase A: joints 0..8 (bones 0..7) =================
    if (tid < nvalid) {
        float ev[24], L[8];
        const float4* ge4 = (const float4*)(euler + (size_t)t * 48);
        const float4* gb4 = (const float4*)(blen + (size_t)t * 16);
#pragma unroll
        for (int q = 0; q < 6; ++q) {
            float4 v = ge4[q];
            ev[4*q+0] = v.x; ev[4*q+1] = v.y; ev[4*q+2] = v.z; ev[4*q+3] = v.w;
        }
        {
            float4 v = gb4[0];
            L[0] = v.x; L[1] = v.y; L[2] = v.z; L[3] = v.w;
            v = gb4[1];
            L[4] = v.x; L[5] = v.y; L[6] = v.z; L[7] = v.w;
        }

        float* o = s_o + tid * CA;
        float Ma[9], Mb[9], R[9];
        float px, py, pz;

        // root (joint 0)
        o[0] = 0.f; o[1] = 0.f; o[2] = 0.f;

        // chain 0 -> 1 -> 2 -> 3 (bones 0,1,2)
        euler_rot3(ev + 0, Ma);
        px = L[0]*Ma[6]; py = L[0]*Ma[7]; pz = L[0]*Ma[8];
        o[3] = px; o[4] = py; o[5] = pz;
        euler_rot3(ev + 3, R); mm3(Ma, R, Mb);
        px += L[1]*Mb[6]; py += L[1]*Mb[7]; pz += L[1]*Mb[8];
        o[6] = px; o[7] = py; o[8] = pz;
        euler_rot3(ev + 6, R); mm3(Mb, R, Ma);
        px += L[2]*Ma[6]; py += L[2]*Ma[7]; pz += L[2]*Ma[8];
        o[9] = px; o[10] = py; o[11] = pz;

        // chain 0 -> 4 -> 5 -> 6 (bones 3,4,5)
        euler_rot3(ev + 9, Ma);
        px = L[3]*Ma[6]; py = L[3]*Ma[7]; pz = L[3]*Ma[8];
        o[12] = px; o[13] = py; o[14] = pz;
        euler_rot3(ev + 12, R); mm3(Ma, R, Mb);
        px += L[4]*Mb[6]; py += L[4]*Mb[7]; pz += L[4]*Mb[8];
        o[15] = px; o[16] = py; o[17] = pz;
        euler_rot3(ev + 15, R); mm3(Mb, R, Ma);
        px += L[5]*Ma[6]; py += L[5]*Ma[7]; pz += L[5]*Ma[8];
        o[18] = px; o[19] = py; o[20] = pz;

        // spine 0 -> 7 -> 8 (bones 6,7)
        euler_rot3(ev + 18, Ma);
        px = L[6]*Ma[6]; py = L[6]*Ma[7]; pz = L[6]*Ma[8];
        o[21] = px; o[22] = py; o[23] = pz;
        euler_rot3(ev + 21, R); mm3(Ma, R, Mb);   // Mb = M8
        px += L[7]*Mb[6]; py += L[7]*Mb[7]; pz += L[7]*Mb[8];
        o[24] = px; o[25] = py; o[26] = pz;
    }
    __syncthreads();

    // ---- drain A: 27 contiguous floats per sample, lane-consecutive ----
    {
        float* og = out + (size_t)block0 * 51;
        const int tot = nvalid * CA;
        for (int i = tid; i < tot; i += NB) {
            int s = i / CA;              // const div -> magic mul
            int j = i - s * CA;
            og[s * 51 + j] = s_o[i];     // LDS stride == CA -> flat index
        }
    }
    __syncthreads();  // drain reads done before phase B overwrites

    // ================= phase B: joints 9..16 (bones 8..15) =================
    // Self-contained: reload euler floats 16..47 and blen floats 4..15,
    // recompute M8/p8 from bones 6,7. Nothing carried across barriers.
    if (tid < nvalid) {
        float evb[32], Lb[12];
        const float4* ge4 = (const float4*)(euler + (size_t)t * 48);
        const float4* gb4 = (const float4*)(blen + (size_t)t * 16);
#pragma unroll
        for (int q = 0; q < 8; ++q) {
            float4 v = ge4[4 + q];       // floats 16..47
            evb[4*q+0] = v.x; evb[4*q+1] = v.y; evb[4*q+2] = v.z; evb[4*q+3] = v.w;
        }
#pragma unroll
        for (int q = 0; q < 3; ++q) {
            float4 v = gb4[1 + q];       // floats 4..15
            Lb[4*q+0] = v.x; Lb[4*q+1] = v.y; Lb[4*q+2] = v.z; Lb[4*q+3] = v.w;
        }
        // bone i (6..15): euler at evb[3*i-16], length at Lb[i-4]

        float M8[9], Ma[9], Mb[9], R[9];
        float p8x, p8y, p8z;

        // recompute spine: bone6 -> M7, bone7 -> M8, p8
        euler_rot3(evb + 2, Ma);                    // bone 6 (3*6-16=2)
        p8x = Lb[2]*Ma[6]; p8y = Lb[2]*Ma[7]; p8z = Lb[2]*Ma[8];
        euler_rot3(evb + 5, R); mm3(Ma, R, M8);     // bone 7
        p8x += Lb[3]*M8[6]; p8y += Lb[3]*M8[7]; p8z += Lb[3]*M8[8];

        float* o = s_o + tid * CA;       // stride 27, use 24
        float px, py, pz;

        // branch 8 -> 9 -> 10 (bones 8,9)
        euler_rot3(evb + 8, R); mm3(M8, R, Ma);
        px = p8x + Lb[4]*Ma[6]; py = p8y + Lb[4]*Ma[7]; pz = p8z + Lb[4]*Ma[8];
        o[0] = px; o[1] = py; o[2] = pz;
        euler_rot3(evb + 11, R); mm3(Ma, R, Mb);
        px += Lb[5]*Mb[6]; py += Lb[5]*Mb[7]; pz += Lb[5]*Mb[8];
        o[3] = px; o[4] = py; o[5] = pz;

        // branch 8 -> 11 -> 12 -> 13 (bones 10,11,12)
        euler_rot3(evb + 14, R); mm3(M8, R, Ma);
        px = p8x + Lb[6]*Ma[6]; py = p8y + Lb[6]*Ma[7]; pz = p8z + Lb[6]*Ma[8];
        o[6] = px; o[7] = py; o[8] = pz;
        euler_rot3(evb + 17, R); mm3(Ma, R, Mb);
        px += Lb[7]*Mb[6]; py += Lb[7]*Mb[7]; pz += Lb[7]*Mb[8];
        o[9] = px; o[10] = py; o[11] = pz;
        euler_rot3(evb + 20, R); mm3(Mb, R, Ma);
        px += Lb[8]*Ma[6]; py += Lb[8]*Ma[7]; pz += Lb[8]*Ma[8];
        o[12] = px; o[13] = py; o[14] = pz;

        // branch 8 -> 14 -> 15 -> 16 (bones 13,14,15)
        euler_rot3(evb + 23, R); mm3(M8, R, Ma);
        px = p8x + Lb[9]*Ma[6]; py = p8y + Lb[9]*Ma[7]; pz = p8z + Lb[9]*Ma[8];
        o[15] = px; o[16] = py; o[17] = pz;
        euler_rot3(evb + 26, R); mm3(Ma, R, Mb);
        px += Lb[10]*Mb[6]; py += Lb[10]*Mb[7]; pz += Lb[10]*Mb[8];
        o[18] = px; o[19] = py; o[20] = pz;
        euler_rot3(evb + 29, R); mm3(Mb, R, Ma);
        px += Lb[11]*Ma[6]; py += Lb[11]*Ma[7]; pz += Lb[11]*Ma[8];
        o[21] = px; o[22] = py; o[23] = pz;
    }
    __syncthreads();

    // ---- drain B: 24 contiguous floats per sample, lane-consecutive ----
    {
        float* og = out + (size_t)block0 * 51 + CA;
        const int tot = nvalid * CB;
        for (int i = tid; i < tot; i += NB) {
            int s = i / CB;              // const div -> magic mul
            int j = i - s * CB;
            og[s * 51 + j] = s_o[s * CA + j];
        }
    }
}

extern "C" void kernel_launch(void* const* d_in, const int* in_sizes, int n_in,
                              void* d_out, int out_size, void* d_ws, size_t ws_size,
                              hipStream_t stream) {
    const float* euler = (const float*)d_in[0];   // (N,16,3) fp32
    const float* blen  = (const float*)d_in[1];   // (N,16,1) fp32
    float* out = (float*)d_out;                   // (N,17,3) fp32

    const int n    = in_sizes[0] / 48;
    const int grid = (n + NB - 1) / NB;
    fk17_kernel<<<grid, NB, 0, stream>>>(euler, blen, out, n);
}

// Round 5
// 200.227 us; speedup vs baseline: 1.3344x; 1.2693x over previous
//
#include <hip/hip_runtime.h>

// Forward kinematics, H36M 17-joint skeleton. One thread = one sample.
// R8: give the register allocator room so the 16 input float4 loads can
// actually stay in flight.
// Accounting that R0-R4 missed: at VGPR=68 the kernel CANNOT hold the 64
// loaded floats plus ~45 live matrix floats -> the compiler was sinking each
// load just-in-time into the bone chain = 16 serial latency exposures/wave.
// R4's sched_barrier couldn't help: with 68 regs, pinning issue order just
// forces immediate vmcnt waits to recycle destination registers.
// Fix: __launch_bounds__(64,3) -> VGPR cap ~170. This is FREE: LDS
// (64*51*4 = 13056 B/block) caps at 12 blocks/CU = 12 waves/CU, and
// 3 waves/SIMD = 12 waves/CU -- identical ceiling.
// Also: single-wave blocks (barrier trivial, no inter-wave coupling), drain
// is the wave's own contiguous 13056 B region (= exactly 204 full lines,
// float4, 16B-aligned) -> WRITE_SIZE stays exact. No phase split, no reload
// (R7 proved phase-B reloads miss L2/L3 and cost +88MB of HBM), no
// cross-barrier float state (R5 proved that spills).

#define NB 64

__device__ __forceinline__ void mm3(const float A[9], const float B[9], float C[9]) {
#pragma unroll
    for (int r = 0; r < 3; ++r) {
        C[3*r+0] = A[3*r+0]*B[0] + A[3*r+1]*B[3] + A[3*r+2]*B[6];
        C[3*r+1] = A[3*r+0]*B[1] + A[3*r+1]*B[4] + A[3*r+2]*B[7];
        C[3*r+2] = A[3*r+0]*B[2] + A[3*r+1]*B[5] + A[3*r+2]*B[8];
    }
}

// R = Rx(a) @ Ry(b) @ Rz(c)  (pytorch3d euler_angles_to_matrix 'XYZ'), row-major
__device__ __forceinline__ void euler_rot(const float* __restrict__ ev, int i, float R[9]) {
    float a = ev[3*i+0], b = ev[3*i+1], c = ev[3*i+2];
    float sx, cx, sy, cy, sz, cz;
    __sincosf(a, &sx, &cx);
    __sincosf(b, &sy, &cy);
    __sincosf(c, &sz, &cz);
    R[0] = cy*cz;             R[1] = -cy*sz;            R[2] = sy;
    R[3] = sx*sy*cz + cx*sz;  R[4] = -sx*sy*sz + cx*cz; R[5] = -sx*cy;
    R[6] = -cx*sy*cz + sx*sz; R[7] = cx*sy*sz + sx*cz;  R[8] = cx*cy;
}

__global__ void __launch_bounds__(NB, 3)
fk17_kernel(const float* __restrict__ euler, const float* __restrict__ blen,
            float* __restrict__ out, int n)
{
    __shared__ float s_o[NB * 51];  // 13056 B; stride 51 (odd) -> conflict-free

    const int tid    = threadIdx.x;
    const int block0 = blockIdx.x * NB;
    const int nvalid = min(NB, n - block0);
    const int t      = block0 + tid;

    if (tid < nvalid) {
        // ---- batched input loads: 12 + 4 independent float4s.
        // With the (64,3) register budget these results can ALL stay live ->
        // one latency exposure instead of 16.
        float ev[48];
        const float4* ge4 = (const float4*)(euler + (size_t)t * 48);
#pragma unroll
        for (int q = 0; q < 12; ++q) {
            float4 v = ge4[q];
            ev[4*q+0] = v.x; ev[4*q+1] = v.y; ev[4*q+2] = v.z; ev[4*q+3] = v.w;
        }
        float L[16];
        const float4* gb4 = (const float4*)(blen + (size_t)t * 16);
#pragma unroll
        for (int q = 0; q < 4; ++q) {
            float4 v = gb4[q];
            L[4*q+0] = v.x; L[4*q+1] = v.y; L[4*q+2] = v.z; L[4*q+3] = v.w;
        }

        float* o = s_o + tid * 51;
        float Ma[9], Mb[9], M8[9], R[9];
        float px, py, pz, p8x, p8y, p8z;

        // root (joint 0)
        o[0] = 0.f; o[1] = 0.f; o[2] = 0.f;

        // --- chain: 0 -> 1 -> 2 -> 3 (bones 0,1,2) ---
        euler_rot(ev, 0, Ma);
        px = L[0]*Ma[6]; py = L[0]*Ma[7]; pz = L[0]*Ma[8];
        o[3] = px; o[4] = py; o[5] = pz;
        euler_rot(ev, 1, R); mm3(Ma, R, Mb);
        px += L[1]*Mb[6]; py += L[1]*Mb[7]; pz += L[1]*Mb[8];
        o[6] = px; o[7] = py; o[8] = pz;
        euler_rot(ev, 2, R); mm3(Mb, R, Ma);
        px += L[2]*Ma[6]; py += L[2]*Ma[7]; pz += L[2]*Ma[8];
        o[9] = px; o[10] = py; o[11] = pz;

        // --- chain: 0 -> 4 -> 5 -> 6 (bones 3,4,5) ---
        euler_rot(ev, 3, Ma);
        px = L[3]*Ma[6]; py = L[3]*Ma[7]; pz = L[3]*Ma[8];
        o[12] = px; o[13] = py; o[14] = pz;
        euler_rot(ev, 4, R); mm3(Ma, R, Mb);
        px += L[4]*Mb[6]; py += L[4]*Mb[7]; pz += L[4]*Mb[8];
        o[15] = px; o[16] = py; o[17] = pz;
        euler_rot(ev, 5, R); mm3(Mb, R, Ma);
        px += L[5]*Ma[6]; py += L[5]*Ma[7]; pz += L[5]*Ma[8];
        o[18] = px; o[19] = py; o[20] = pz;

        // --- spine: 0 -> 7 -> 8 (bones 6,7) ---
        euler_rot(ev, 6, Ma);
        px = L[6]*Ma[6]; py = L[6]*Ma[7]; pz = L[6]*Ma[8];
        o[21] = px; o[22] = py; o[23] = pz;
        euler_rot(ev, 7, R); mm3(Ma, R, M8);         // M8 = accum at joint 8
        px += L[7]*M8[6]; py += L[7]*M8[7]; pz += L[7]*M8[8];
        o[24] = px; o[25] = py; o[26] = pz;
        p8x = px; p8y = py; p8z = pz;

        // --- branch: 8 -> 9 -> 10 (bones 8,9) ---
        euler_rot(ev, 8, R); mm3(M8, R, Ma);
        px = p8x + L[8]*Ma[6]; py = p8y + L[8]*Ma[7]; pz = p8z + L[8]*Ma[8];
        o[27] = px; o[28] = py; o[29] = pz;
        euler_rot(ev, 9, R); mm3(Ma, R, Mb);
        px += L[9]*Mb[6]; py += L[9]*Mb[7]; pz += L[9]*Mb[8];
        o[30] = px; o[31] = py; o[32] = pz;

        // --- branch: 8 -> 11 -> 12 -> 13 (bones 10,11,12) ---
        euler_rot(ev, 10, R); mm3(M8, R, Ma);
        px = p8x + L[10]*Ma[6]; py = p8y + L[10]*Ma[7]; pz = p8z + L[10]*Ma[8];
        o[33] = px; o[34] = py; o[35] = pz;
        euler_rot(ev, 11, R); mm3(Ma, R, Mb);
        px += L[11]*Mb[6]; py += L[11]*Mb[7]; pz += L[11]*Mb[8];
        o[36] = px; o[37] = py; o[38] = pz;
        euler_rot(ev, 12, R); mm3(Mb, R, Ma);
        px += L[12]*Ma[6]; py += L[12]*Ma[7]; pz += L[12]*Ma[8];
        o[39] = px; o[40] = py; o[41] = pz;

        // --- branch: 8 -> 14 -> 15 -> 16 (bones 13,14,15) ---
        euler_rot(ev, 13, R); mm3(M8, R, Ma);
        px = p8x + L[13]*Ma[6]; py = p8y + L[13]*Ma[7]; pz = p8z + L[13]*Ma[8];
        o[42] = px; o[43] = py; o[44] = pz;
        euler_rot(ev, 14, R); mm3(Ma, R, Mb);
        px += L[14]*Mb[6]; py += L[14]*Mb[7]; pz += L[14]*Mb[8];
        o[45] = px; o[46] = py; o[47] = pz;
        euler_rot(ev, 15, R); mm3(Mb, R, Ma);
        px += L[15]*Ma[6]; py += L[15]*Ma[7]; pz += L[15]*Ma[8];
        o[48] = px; o[49] = py; o[50] = pz;
    }
    __syncthreads();  // single-wave block: trivially cheap, orders LDS

    // ---- drain: this wave's contiguous 64*51 floats = 816 float4s
    //      = exactly 204 full 64B lines, 16B-aligned. Fully coalesced. ----
    if (nvalid == NB) {
        const float4* so4 = (const float4*)s_o;
        float4*       og4 = (float4*)(out + (size_t)block0 * 51);
#pragma unroll
        for (int k = 0; k < 13; ++k) {           // 816 = 64*12 + 48
            int i4 = tid + 64 * k;
            if (k < 12 || i4 < 816) og4[i4] = so4[i4];
        }
    } else {
        float* og = out + (size_t)block0 * 51;
        const int tot = nvalid * 51;
        for (int i = tid; i < tot; i += NB)
            og[i] = s_o[i];
    }
}

extern "C" void kernel_launch(void* const* d_in, const int* in_sizes, int n_in,
                              void* d_out, int out_size, void* d_ws, size_t ws_size,
                              hipStream_t stream) {
    const float* euler = (const float*)d_in[0];   // (N,16,3) fp32
    const float* blen  = (const float*)d_in[1];   // (N,16,1) fp32
    float* out = (float*)d_out;                   // (N,17,3) fp32

    const int n    = in_sizes[0] / 48;
    const int grid = (n + NB - 1) / NB;
    fk17_kernel<<<grid, NB, 0, stream>>>(euler, blen, out, n);
}